// Round 27
// baseline (185.252 us; speedup 1.0000x reference)
//
#include <hip/hip_runtime.h>
#include <stdint.h>

// WebAttention fused block for MI355X (gfx950).
// R27: pack_mask -> ballot-coalesced. Old code: each thread read 32 floats at
//      lane-stride 128B => every load a 64-line gather (same pathology class
//      as R20 GEMM / R22 attn V; 16 MB f32 at gather rate). New: one wave per
//      mask row, lanes read contiguous floats, __ballot packs 64 keys/iter,
//      lanes 0/32 store the two u32 words (transposed layout unchanged).
//      Everything else identical to R26.

typedef unsigned short u16;
typedef unsigned short u16x4 __attribute__((ext_vector_type(4)));
typedef unsigned short u16x8 __attribute__((ext_vector_type(8)));
typedef __bf16 bf16x8 __attribute__((ext_vector_type(8)));
typedef float f32x4 __attribute__((ext_vector_type(4)));
typedef float f32x16 __attribute__((ext_vector_type(16)));

#define SLEN 2048
#define HIDDEN 2048
#define QKVN 3072   // 2048 Q + 512 K + 512 V
// Q pre-scale: 1/sqrt(64) * log2(e)  -> scores land in exp2 domain
#define QSCALE 0.18033688011112042f

#define CFENCE() asm volatile("" ::: "memory")

__device__ __forceinline__ u16 f2bf(float x) {  // RNE, matches numpy/JAX
  uint32_t u = __float_as_uint(x);
  return (u16)((u + 0x7FFFu + ((u >> 16) & 1u)) >> 16);
}

__device__ __forceinline__ float bf2f(u16 x) {
  return __uint_as_float((uint32_t)x << 16);
}

__device__ __forceinline__ uint32_t cvtpk_bf16(float lo, float hi) {
  uint32_t r;
  asm("v_cvt_pk_bf16_f32 %0, %1, %2" : "=v"(r) : "v"(lo), "v"(hi));
  return r;
}

// raw hardware exp2 (D = 2^S0). VALU deps are HW-interlocked on CDNA.
__device__ __forceinline__ float fast_exp2(float x) {
  float r;
  asm("v_exp_f32 %0, %1" : "=v"(r) : "v"(x));
  return r;
}

// Cross-half (lane ^ 32) sum: {r[0],r[1]} = {self, partner} as a set.
__device__ __forceinline__ float xhalf_sum(float x) {
  auto r = __builtin_amdgcn_permlane32_swap(__float_as_uint(x), __float_as_uint(x),
                                            false, false);
  return __uint_as_float(r[0]) + __uint_as_float(r[1]);
}

__device__ __forceinline__ void gload_lds16(const void* g, void* l) {
  __builtin_amdgcn_global_load_lds(
      (const __attribute__((address_space(1))) void*)g,
      (__attribute__((address_space(3))) void*)l, 16, 0, 0);
}

// ---------------- prep_all: cvt + 4 transposes + ballot pack_mask ----------
__device__ __forceinline__ void transpose_tile(const float* in, int ldin,
                                               u16* out, int ldout,
                                               int k0, int n0, int tid,
                                               float (*tile)[33]) {
  int x = tid & 31, y = tid >> 5;  // y in 0..7
#pragma unroll
  for (int i = 0; i < 32; i += 8)
    tile[y + i][x] = in[(size_t)(k0 + y + i) * ldin + n0 + x];
  __syncthreads();
#pragma unroll
  for (int i = 0; i < 32; i += 8)
    out[(size_t)(n0 + y + i) * ldout + k0 + x] = f2bf(tile[x][y + i]);
}

__global__ __launch_bounds__(256) void prep_all(const float* __restrict__ hidden,
                                                u16* __restrict__ hbf,
                                                const float* __restrict__ Wq,
                                                const float* __restrict__ Wk,
                                                const float* __restrict__ Wv,
                                                const float* __restrict__ Wo,
                                                u16* __restrict__ Wcat,
                                                u16* __restrict__ Wot,
                                                const float* __restrict__ webmask,
                                                uint32_t* __restrict__ mbits) {
  __shared__ float tile[32][33];
  const int b = blockIdx.x, tid = threadIdx.x;
  if (b < 4096) {
    int idx = (b * 256 + tid) * 4;
    float4 v = *(const float4*)(hidden + idx);
    u16x4 o;
    o[0] = f2bf(v.x); o[1] = f2bf(v.y); o[2] = f2bf(v.z); o[3] = f2bf(v.w);
    *(u16x4*)(hbf + idx) = o;
  } else if (b < 8192) {
    int t = b - 4096;
    transpose_tile(Wq, 2048, Wcat, 2048, (t & 63) * 32, (t >> 6) * 32, tid, tile);
  } else if (b < 9216) {
    int t = b - 8192;
    transpose_tile(Wk, 512, Wcat + (size_t)2048 * 2048, 2048,
                   (t & 63) * 32, (t >> 6) * 32, tid, tile);
  } else if (b < 10240) {
    int t = b - 9216;
    transpose_tile(Wv, 512, Wcat + (size_t)2560 * 2048, 2048,
                   (t & 63) * 32, (t >> 6) * 32, tid, tile);
  } else if (b < 14336) {
    int t = b - 10240;
    transpose_tile(Wo, 2048, Wot, 2048, (t & 63) * 32, (t >> 6) * 32, tid, tile);
  } else {
    // ballot-coalesced web-mask pack: wave -> one source row s; 32 iters of
    // 64 contiguous lanes; mbitsT[kword][s] (transposed) gets 2 words/iter.
    int t = b - 14336;               // 0..511
    int s = t * 4 + (tid >> 6);      // row index
    int lane = tid & 63;
    const float* rowp = webmask + (size_t)s * 2048;
    for (int it = 0; it < 32; ++it) {
      float v = rowp[it * 64 + lane];
      unsigned long long bm = __ballot(v > -0.5f);
      if (lane == 0)
        mbits[(size_t)(2 * it) * 2048 + s] = (uint32_t)bm;
      if (lane == 32)
        mbits[(size_t)(2 * it + 1) * 2048 + s] = (uint32_t)(bm >> 32);
    }
  }
}

// ---------------- TN GEMM: C[M=2048][N] = A[M][K] * B[N][K]^T ----------------
// Tile 128 x BN (BN = WN*32), BK=64, 4 waves (2x2), 2-buffer ring + counted
// vmcnt + fenced raw barriers. Coalesced staging map (R20): chunk c ->
// r=(c>>3)&15, kq=c&7 fastest; source col pre-swizzled kq^(r&7); ds_read
// applies the same XOR. XCD map: 8bm x 4bn rectangle per XCD. grid = 256.
template <int WN, int OUTBF>
__global__ __launch_bounds__(256) void gemm_tn(const u16* __restrict__ A,
                                               const u16* __restrict__ B,
                                               void* __restrict__ Cv,
                                               int N, int K) {
  constexpr int BN = WN * 32;
  __shared__ u16 As[2][128 * 64];   // 2 x 16 KB
  __shared__ u16 Bs[2][BN * 64];    // 2 x BN/8 KB
  const int tid = threadIdx.x;
  const int w = tid >> 6, l = tid & 63;
  const int lin = blockIdx.x;
  const int xcd = lin & 7, pos = lin >> 3;
  const int bm = ((xcd & 1) << 3) + (pos & 7);
  const int bn = ((xcd >> 1) << 2) + (pos >> 3);
  const int wr = w >> 1, wc = w & 1;

  f32x4 acc[4][WN] = {};

  int rowA[4], colA[4], ldsA[4];
#pragma unroll
  for (int g = 0; g < 4; ++g) {
    int c = g * 256 + w * 64 + l;
    rowA[g] = ((c >> 7) << 4) + ((c >> 3) & 15);
    colA[g] = ((c & 7) ^ ((c >> 3) & 7)) * 8;
    ldsA[g] = (g * 256 + w * 64) * 8;
  }
  int rowB[WN], colB[WN], ldsB[WN];
#pragma unroll
  for (int g = 0; g < WN; ++g) {
    int c = g * 256 + w * 64 + l;
    rowB[g] = ((c >> 7) << 4) + ((c >> 3) & 15);
    colB[g] = ((c & 7) ^ ((c >> 3) & 7)) * 8;
    ldsB[g] = (g * 256 + w * 64) * 8;
  }
  const u16* Arow = A + (size_t)(bm * 128) * K;
  const u16* Brow = B + (size_t)(bn * BN) * K;

  auto stage = [&](int buf, int k0) {
#pragma unroll
    for (int g = 0; g < 4; ++g)
      gload_lds16(Arow + (size_t)rowA[g] * K + k0 + colA[g], &As[buf][ldsA[g]]);
#pragma unroll
    for (int g = 0; g < WN; ++g)
      gload_lds16(Brow + (size_t)rowB[g] * K + k0 + colB[g], &Bs[buf][ldsB[g]]);
  };

  const int nk = K >> 6;
  stage(0, 0);

  for (int k = 0; k < nk; ++k) {
    CFENCE(); __builtin_amdgcn_s_barrier(); CFENCE();  // compute k-1 done by all
    if (k + 1 < nk) {
      stage((k + 1) & 1, (k + 1) * 64);
      if constexpr (WN == 6) asm volatile("s_waitcnt vmcnt(10)" ::: "memory");
      else                   asm volatile("s_waitcnt vmcnt(8)" ::: "memory");
    } else {
      asm volatile("s_waitcnt vmcnt(0)" ::: "memory");
    }
    CFENCE(); __builtin_amdgcn_s_barrier(); CFENCE();  // tile k visible to all
    const int cur = k & 1;
#pragma unroll
    for (int ks = 0; ks < 2; ++ks) {
      const int xq = ((ks * 4 + (l >> 4)) ^ (l & 7)) * 8;
      const int rbase = (l & 15) * 64 + xq;
      bf16x8 af[4], bfr[WN];
#pragma unroll
      for (int mi = 0; mi < 4; ++mi)
        af[mi] = *(const bf16x8*)&As[cur][(wr * 4 + mi) * 1024 + rbase];
#pragma unroll
      for (int ni = 0; ni < WN; ++ni)
        bfr[ni] = *(const bf16x8*)&Bs[cur][(wc * WN + ni) * 1024 + rbase];
#pragma unroll
      for (int mi = 0; mi < 4; ++mi)
#pragma unroll
        for (int ni = 0; ni < WN; ++ni)
          acc[mi][ni] = __builtin_amdgcn_mfma_f32_16x16x32_bf16(af[mi], bfr[ni],
                                                                acc[mi][ni], 0, 0, 0);
    }
  }
  const int cr = (l >> 4) * 4, cc = l & 15;
#pragma unroll
  for (int mi = 0; mi < 4; ++mi) {
    int row0 = bm * 128 + wr * 64 + mi * 16 + cr;
#pragma unroll
    for (int ni = 0; ni < WN; ++ni) {
      int col = bn * BN + wc * (WN * 16) + ni * 16 + cc;
      if constexpr (OUTBF) {
        u16* C = (u16*)Cv;
#pragma unroll
        for (int i = 0; i < 4; ++i)
          C[(size_t)(row0 + i) * N + col] = f2bf(acc[mi][ni][i]);
      } else {
        float* C = (float*)Cv;
#pragma unroll
        for (int i = 0; i < 4; ++i)
          C[(size_t)(row0 + i) * N + col] = acc[mi][ni][i];
      }
    }
  }
}

// ---------------- RoPE/RMSNorm + V-transpose (bf16 qkv input) ----------------
// V output layout: Vt[kv][kb=64][d=64][k=32]  (4KB contiguous per block)
__global__ __launch_bounds__(256) void rope_vtrans(const u16* __restrict__ qkv,
                                                   const float* __restrict__ qw,
                                                   const float* __restrict__ kw,
                                                   u16* __restrict__ Qo,
                                                   u16* __restrict__ Ko,
                                                   u16* __restrict__ Vt) {
  __shared__ float tile[32][65];
  const int b = blockIdx.x, tid = threadIdx.x;
  if (b < 20480) {
    int s = (b & 511) * 4 + (tid >> 6);
    int hh = b >> 9;
    int d = tid & 63;
    bool isq = hh < 32;
    int col = isq ? hh * 64 + d : 2048 + (hh - 32) * 64 + d;
    float x = bf2f(qkv[(size_t)s * QKVN + col]);
    int i = d & 31;
    float inv_freq = exp2f(-(float)i * (13.287712379549449f / 32.0f));
    float ang = (float)s * inv_freq;
    float sn, cs;
    __sincosf(ang, &sn, &cs);
    float partner = __shfl_xor(x, 32, 64);
    float y = (d < 32) ? (x * cs - partner * sn) : (x * cs + partner * sn);
    float ss = y * y;
#pragma unroll
    for (int off = 32; off; off >>= 1) ss += __shfl_xor(ss, off, 64);
    float r = rsqrtf(ss * (1.0f / 64.0f) + 1e-6f);
    float o = y * r * (isq ? qw[d] : kw[d]);
    if (isq) Qo[((size_t)hh * SLEN + s) * 64 + d] = f2bf(o * QSCALE);
    else     Ko[((size_t)(hh - 32) * SLEN + s) * 64 + d] = f2bf(o);
  } else {
    int t = b - 20480;
    int kv = t >> 6;
    int s0 = (t & 63) * 32;
    int d = tid & 63, r4 = tid >> 6;
#pragma unroll
    for (int i = 0; i < 32; i += 4)
      tile[i + r4][d] = bf2f(qkv[(size_t)(s0 + i + r4) * QKVN + 2560 + kv * 64 + d]);
    __syncthreads();
    int dr = tid >> 2, sc = (tid & 3) * 8;
    u16x8 o;
#pragma unroll
    for (int j = 0; j < 8; ++j) o[j] = f2bf(tile[sc + j][dr]);
    *(u16x8*)(Vt + (((size_t)kv * 64 + (s0 >> 5)) * 64 + dr) * 32 + sc) = o;
  }
}

// ---------------- flash attention: one dispatch, paired q-tiles ----------------
// grid 1024: head h = xcd*4 + (pos&3) (one kv head/XCD), pair j = pos>>2.
// Processes qt = 63-j then qt = j (LDS reused), 4-wave in-block split-K.
// Fixed-scale softmax: p = v_exp(s); masked -> 0. Combine = sum(acc)/sum(l).
// 2-stage ping-pong register sets (R26).
__global__ __launch_bounds__(256) void attn_fused(const u16* __restrict__ Q,
                                                  const u16* __restrict__ Kh,
                                                  const u16* __restrict__ Vt,
                                                  const uint32_t* __restrict__ mbits,
                                                  u16* __restrict__ Aout) {
  __shared__ float accS[4 * 32 * 64];  // 32 KB
  __shared__ float lS[4 * 32];         // 0.5 KB
  const int w = threadIdx.x >> 6, l = threadIdx.x & 63;
  const int lin = blockIdx.x;
  const int xcd = lin & 7, pos = lin >> 3;
  const int h = xcd * 4 + (pos & 3);   // 4 heads/XCD = one kv head
  const int j = pos >> 2;              // pair index 0..31
  const int hkv = h >> 2;
  const bool web = (h >= 16);
  const int l31 = l & 31, hi = l >> 5;
  const int qrel = l31 - 4 * hi;  // diag-block causal: keep iff ki <= qrel

  const u16* Kp = Kh + ((size_t)hkv * SLEN + l31) * 64 + hi * 8;
  const u16* Vbase = Vt + (size_t)hkv * 64 * SLEN;   // blocked: +kb*2048
  const int voff = l31 * 32 + hi * 8;

#define LOADSET(P, kbn)                                                         \
  do {                                                                          \
    const u16* knp_ = Kp + (size_t)(kbn) * 2048;                                \
    P##k0 = *(const bf16x8*)(knp_);                                             \
    P##k1 = *(const bf16x8*)(knp_ + 16);                                        \
    P##k2 = *(const bf16x8*)(knp_ + 32);                                        \
    P##k3 = *(const bf16x8*)(knp_ + 48);                                        \
    const u16* vnp_ = Vbase + (size_t)(kbn) * 2048 + voff;                      \
    P##v0 = *(const bf16x8*)(vnp_);                                             \
    P##v1 = *(const bf16x8*)(vnp_ + 16);                                        \
    P##v2 = *(const bf16x8*)(vnp_ + 1024);                                      \
    P##v3 = *(const bf16x8*)(vnp_ + 1024 + 16);                                 \
    if (web) P##m = mrowT[(size_t)(kbn) * 2048];                                \
  } while (0)

#define COMPUTE(P, kbv)                                                         \
  do {                                                                          \
    const int kb_ = (kbv);                                                      \
    __builtin_amdgcn_s_setprio(1);                                              \
    f32x16 s = {};                                                              \
    s = __builtin_amdgcn_mfma_f32_32x32x16_bf16(P##k0, qf0, s, 0, 0, 0);        \
    s = __builtin_amdgcn_mfma_f32_32x32x16_bf16(P##k1, qf1, s, 0, 0, 0);        \
    s = __builtin_amdgcn_mfma_f32_32x32x16_bf16(P##k2, qf2, s, 0, 0, 0);        \
    s = __builtin_amdgcn_mfma_f32_32x32x16_bf16(P##k3, qf3, s, 0, 0, 0);        \
    __builtin_amdgcn_s_setprio(0);                                              \
    if (web) {                                                                  \
      uint32_t word = P##m >> (hi * 4);                                         \
      if (kb_ == qt) {                                                          \
        _Pragma("unroll")                                                       \
        for (int r = 0; r < 16; ++r) {                                          \
          const int ki = (r & 3) + 8 * (r >> 2);                                \
          bool keep = ((word >> ki) & 1u) && (ki <= qrel);                      \
          s[r] = keep ? s[r] : -1e9f;                                           \
        }                                                                       \
      } else {                                                                  \
        _Pragma("unroll")                                                       \
        for (int r = 0; r < 16; ++r) {                                          \
          const int ki = (r & 3) + 8 * (r >> 2);                                \
          s[r] = ((word >> ki) & 1u) ? s[r] : -1e9f;                            \
        }                                                                       \
      }                                                                         \
    } else if (kb_ == qt) {                                                     \
      _Pragma("unroll")                                                         \
      for (int r = 0; r < 16; ++r) {                                            \
        const int ki = (r & 3) + 8 * (r >> 2);                                  \
        s[r] = (ki <= qrel) ? s[r] : -1e9f;                                     \
      }                                                                         \
    }                                                                           \
    f32x16 p;                                                                   \
    _Pragma("unroll")                                                           \
    for (int r = 0; r < 16; ++r) p[r] = fast_exp2(s[r]);                        \
    float rs = ((p[0] + p[1]) + (p[2] + p[3])) + ((p[4] + p[5]) + (p[6] + p[7]))\
             + ((p[8] + p[9]) + (p[10] + p[11]))                                \
             + ((p[12] + p[13]) + (p[14] + p[15]));                             \
    llh += rs;                                                                  \
    uint32_t a0 = cvtpk_bf16(p[0], p[1]),   b0 = cvtpk_bf16(p[2], p[3]);        \
    uint32_t c0 = cvtpk_bf16(p[4], p[5]),   d0 = cvtpk_bf16(p[6], p[7]);        \
    uint32_t a1 = cvtpk_bf16(p[8], p[9]),   b1 = cvtpk_bf16(p[10], p[11]);      \
    uint32_t c1 = cvtpk_bf16(p[12], p[13]), d1 = cvtpk_bf16(p[14], p[15]);      \
    auto r0 = __builtin_amdgcn_permlane32_swap(a0, c0, false, false);           \
    auto r1 = __builtin_amdgcn_permlane32_swap(b0, d0, false, false);           \
    auto r2 = __builtin_amdgcn_permlane32_swap(a1, c1, false, false);           \
    auto r3 = __builtin_amdgcn_permlane32_swap(b1, d1, false, false);           \
    union { uint32_t wv[4]; bf16x8 v; } pf0u, pf1u;                             \
    pf0u.wv[0] = r0[0]; pf0u.wv[1] = r1[0]; pf0u.wv[2] = r0[1]; pf0u.wv[3] = r1[1]; \
    pf1u.wv[0] = r2[0]; pf1u.wv[1] = r3[0]; pf1u.wv[2] = r2[1]; pf1u.wv[3] = r3[1]; \
    __builtin_amdgcn_s_setprio(1);                                              \
    acc0 = __builtin_amdgcn_mfma_f32_32x32x16_bf16(P##v0, pf0u.v, acc0, 0, 0, 0); \
    acc0 = __builtin_amdgcn_mfma_f32_32x32x16_bf16(P##v1, pf1u.v, acc0, 0, 0, 0); \
    acc1 = __builtin_amdgcn_mfma_f32_32x32x16_bf16(P##v2, pf0u.v, acc1, 0, 0, 0); \
    acc1 = __builtin_amdgcn_mfma_f32_32x32x16_bf16(P##v3, pf1u.v, acc1, 0, 0, 0); \
    __builtin_amdgcn_s_setprio(0);                                              \
  } while (0)

#pragma unroll
  for (int t = 0; t < 2; ++t) {
    const int qt = t == 0 ? (63 - j) : j;
    const int q0 = qt * 32;
    const int nkb = qt + 1;
    const uint32_t* mrowT = mbits + q0 + l31;        // transposed: +kword*2048

    const u16* Qp = Q + ((size_t)h * SLEN + q0 + l31) * 64 + hi * 8;
    bf16x8 qf0 = *(const bf16x8*)(Qp);
    bf16x8 qf1 = *(const bf16x8*)(Qp + 16);
    bf16x8 qf2 = *(const bf16x8*)(Qp + 32);
    bf16x8 qf3 = *(const bf16x8*)(Qp + 48);

    f32x16 acc0 = {}, acc1 = {};   // O^T[d][q]
    float llh = 0.f;               // this half's sum; combined at end

    if (w < nkb) {
      bf16x8 Ak0, Ak1, Ak2, Ak3, Av0, Av1, Av2, Av3;
      bf16x8 Bk0, Bk1, Bk2, Bk3, Bv0, Bv1, Bv2, Bv3;
      uint32_t Am = 0, Bm = 0;
      int kb = w;
      LOADSET(A, kb);
      while (true) {
        if (kb + 4 < nkb) LOADSET(B, kb + 4);
        COMPUTE(A, kb);
        kb += 4;
        if (kb >= nkb) break;
        if (kb + 4 < nkb) LOADSET(A, kb + 4);
        COMPUTE(B, kb);
        kb += 4;
        if (kb >= nkb) break;
      }
    }
    const float ll = xhalf_sum(llh);  // combine halves once
    // ---- stash per-wave state in LDS (raw acc + l) ----
    if (hi == 0) lS[w * 32 + l31] = ll;
    float* wbase = accS + w * 2048 + (l31 << 6);
    const int sw = (l31 & 15) << 2;  // swizzle: d ^= sw
#pragma unroll
    for (int tt = 0; tt < 4; ++tt) {
      int dA = (8 * tt + 4 * hi) ^ sw;
      int dB = (32 + 8 * tt + 4 * hi) ^ sw;
      float4 v0 = {acc0[4 * tt], acc0[4 * tt + 1], acc0[4 * tt + 2], acc0[4 * tt + 3]};
      float4 v1 = {acc1[4 * tt], acc1[4 * tt + 1], acc1[4 * tt + 2], acc1[4 * tt + 3]};
      *(float4*)(wbase + dA) = v0;
      *(float4*)(wbase + dB) = v1;
    }
    __syncthreads();
    // ---- combine: thread -> (q = tid&31, d = (tid>>5)*8); plain sum / L ----
    const int q = threadIdx.x & 31;
    const int dd = (threadIdx.x >> 5) * 8;
    float L = (lS[q] + lS[32 + q]) + (lS[64 + q] + lS[96 + q]);
    const int offA = (q << 6) + (dd ^ ((q & 15) << 2));
    const int offB = offA ^ 4;
    float o[8];
    {
      float4 xa = *(float4*)(accS + offA);
      float4 xb = *(float4*)(accS + offB);
      o[0] = xa.x; o[1] = xa.y; o[2] = xa.z; o[3] = xa.w;
      o[4] = xb.x; o[5] = xb.y; o[6] = xb.z; o[7] = xb.w;
    }
#pragma unroll
    for (int ww = 1; ww < 4; ++ww) {
      float4 xa = *(float4*)(accS + ww * 2048 + offA);
      float4 xb = *(float4*)(accS + ww * 2048 + offB);
      o[0] += xa.x; o[1] += xa.y; o[2] += xa.z; o[3] += xa.w;
      o[4] += xb.x; o[5] += xb.y; o[6] += xb.z; o[7] += xb.w;
    }
    const float invL = 1.0f / L;
    uint4 pk;
    pk.x = cvtpk_bf16(o[0] * invL, o[1] * invL);
    pk.y = cvtpk_bf16(o[2] * invL, o[3] * invL);
    pk.z = cvtpk_bf16(o[4] * invL, o[5] * invL);
    pk.w = cvtpk_bf16(o[6] * invL, o[7] * invL);
    *(uint4*)(Aout + (size_t)(q0 + q) * HIDDEN + h * 64 + dd) = pk;
    __syncthreads();  // accS/lS reads done before next tile overwrites
  }
#undef LOADSET
#undef COMPUTE
}

// ---------------- launch ----------------

extern "C" void kernel_launch(void* const* d_in, const int* in_sizes, int n_in,
                              void* d_out, int out_size, void* d_ws, size_t ws_size,
                              hipStream_t stream) {
  const float* hidden  = (const float*)d_in[0];
  const float* webmask = (const float*)d_in[3];
  const float* Wq = (const float*)d_in[4];
  const float* Wk = (const float*)d_in[5];
  const float* Wv = (const float*)d_in[6];
  const float* Wo = (const float*)d_in[7];
  const float* qlnw = (const float*)d_in[8];
  const float* klnw = (const float*)d_in[9];
  float* out = (float*)d_out;

  char* ws = (char*)d_ws;
  u16*      hbf  = (u16*)(ws);                         // 8 MB  hidden bf16
  u16*      Wcat = (u16*)(ws + (8u << 20));            // 12 MB QKV weights^T
  u16*      Wot  = (u16*)(ws + (20u << 20));           // 8 MB  Wo^T
  u16*      qkv  = (u16*)(ws + (28u << 20));           // 12 MB QKV bf16
  u16*      Qh   = (u16*)(ws + (52u << 20));           // 8 MB  Q' (pre-scaled)
  u16*      Kh   = (u16*)(ws + (60u << 20));           // 2 MB  K'
  u16*      Vt   = (u16*)(ws + (62u << 20));           // 2 MB  V^T (blocked)
  u16*      Ao   = (u16*)(ws + (64u << 20));           // 8 MB  attn out bf16
  uint32_t* mb   = (uint32_t*)(ws + (72u << 20));      // 0.5 MB web mask bits (T)

  prep_all<<<14848, 256, 0, stream>>>(hidden, hbf, Wq, Wk, Wv, Wo, Wcat, Wot,
                                      webmask, mb);
  gemm_tn<6, 1><<<256, 256, 0, stream>>>(hbf, Wcat, qkv, QKVN, HIDDEN);  // bf16 C
  rope_vtrans<<<20992, 256, 0, stream>>>(qkv, qlnw, klnw, Qh, Kh, Vt);
  attn_fused<<<1024, 256, 0, stream>>>(Qh, Kh, Vt, mb, Ao);
  gemm_tn<4, 0><<<256, 256, 0, stream>>>(Ao, Wot, out, HIDDEN, HIDDEN);  // fp32 C
}

// Round 28
// 184.057 us; speedup vs baseline: 1.0065x; 1.0065x over previous
//
#include <hip/hip_runtime.h>
#include <stdint.h>

// WebAttention fused block for MI355X (gfx950).
// R28: attn -> 2048 single-tile blocks (work-conserving refill; longest-first)
//      with bf16 LDS partials (accS 32KB->16KB). R27's ballot pack reverted
//      (post-mortem: old per-thread pack reads 32 CONSECUTIVE floats -> L1
//      serves 31/32; not the gather pathology — theory was wrong, measured
//      slightly worse). All else = R26.

typedef unsigned short u16;
typedef unsigned short u16x4 __attribute__((ext_vector_type(4)));
typedef unsigned short u16x8 __attribute__((ext_vector_type(8)));
typedef __bf16 bf16x8 __attribute__((ext_vector_type(8)));
typedef float f32x4 __attribute__((ext_vector_type(4)));
typedef float f32x16 __attribute__((ext_vector_type(16)));

#define SLEN 2048
#define HIDDEN 2048
#define QKVN 3072   // 2048 Q + 512 K + 512 V
// Q pre-scale: 1/sqrt(64) * log2(e)  -> scores land in exp2 domain
#define QSCALE 0.18033688011112042f

#define CFENCE() asm volatile("" ::: "memory")

__device__ __forceinline__ u16 f2bf(float x) {  // RNE, matches numpy/JAX
  uint32_t u = __float_as_uint(x);
  return (u16)((u + 0x7FFFu + ((u >> 16) & 1u)) >> 16);
}

__device__ __forceinline__ float bf2f(u16 x) {
  return __uint_as_float((uint32_t)x << 16);
}

__device__ __forceinline__ uint32_t cvtpk_bf16(float lo, float hi) {
  uint32_t r;
  asm("v_cvt_pk_bf16_f32 %0, %1, %2" : "=v"(r) : "v"(lo), "v"(hi));
  return r;
}

// raw hardware exp2 (D = 2^S0). VALU deps are HW-interlocked on CDNA.
__device__ __forceinline__ float fast_exp2(float x) {
  float r;
  asm("v_exp_f32 %0, %1" : "=v"(r) : "v"(x));
  return r;
}

// Cross-half (lane ^ 32) sum: {r[0],r[1]} = {self, partner} as a set.
__device__ __forceinline__ float xhalf_sum(float x) {
  auto r = __builtin_amdgcn_permlane32_swap(__float_as_uint(x), __float_as_uint(x),
                                            false, false);
  return __uint_as_float(r[0]) + __uint_as_float(r[1]);
}

__device__ __forceinline__ void gload_lds16(const void* g, void* l) {
  __builtin_amdgcn_global_load_lds(
      (const __attribute__((address_space(1))) void*)g,
      (__attribute__((address_space(3))) void*)l, 16, 0, 0);
}

// ---------------- prep_all: cvt + 4 transposes + pack_mask in one kernel -----
__device__ __forceinline__ void transpose_tile(const float* in, int ldin,
                                               u16* out, int ldout,
                                               int k0, int n0, int tid,
                                               float (*tile)[33]) {
  int x = tid & 31, y = tid >> 5;  // y in 0..7
#pragma unroll
  for (int i = 0; i < 32; i += 8)
    tile[y + i][x] = in[(size_t)(k0 + y + i) * ldin + n0 + x];
  __syncthreads();
#pragma unroll
  for (int i = 0; i < 32; i += 8)
    out[(size_t)(n0 + y + i) * ldout + k0 + x] = f2bf(tile[x][y + i]);
}

__global__ __launch_bounds__(256) void prep_all(const float* __restrict__ hidden,
                                                u16* __restrict__ hbf,
                                                const float* __restrict__ Wq,
                                                const float* __restrict__ Wk,
                                                const float* __restrict__ Wv,
                                                const float* __restrict__ Wo,
                                                u16* __restrict__ Wcat,
                                                u16* __restrict__ Wot,
                                                const float* __restrict__ webmask,
                                                uint32_t* __restrict__ mbits) {
  __shared__ float tile[32][33];
  const int b = blockIdx.x, tid = threadIdx.x;
  if (b < 4096) {
    int idx = (b * 256 + tid) * 4;
    float4 v = *(const float4*)(hidden + idx);
    u16x4 o;
    o[0] = f2bf(v.x); o[1] = f2bf(v.y); o[2] = f2bf(v.z); o[3] = f2bf(v.w);
    *(u16x4*)(hbf + idx) = o;
  } else if (b < 8192) {
    int t = b - 4096;
    transpose_tile(Wq, 2048, Wcat, 2048, (t & 63) * 32, (t >> 6) * 32, tid, tile);
  } else if (b < 9216) {
    int t = b - 8192;
    transpose_tile(Wk, 512, Wcat + (size_t)2048 * 2048, 2048,
                   (t & 63) * 32, (t >> 6) * 32, tid, tile);
  } else if (b < 10240) {
    int t = b - 9216;
    transpose_tile(Wv, 512, Wcat + (size_t)2560 * 2048, 2048,
                   (t & 63) * 32, (t >> 6) * 32, tid, tile);
  } else if (b < 14336) {
    int t = b - 10240;
    transpose_tile(Wo, 2048, Wot, 2048, (t & 63) * 32, (t >> 6) * 32, tid, tile);
  } else {
    int w = (b - 14336) * 256 + tid;  // 2048*64 words; s = w>>6, kword = w&63
    const float* p = webmask + (size_t)w * 32;
    uint32_t bits = 0;
#pragma unroll
    for (int j = 0; j < 32; ++j) bits |= (p[j] > -0.5f ? 1u : 0u) << j;
    mbits[(size_t)(w & 63) * 2048 + (w >> 6)] = bits;   // TRANSPOSED [kword][s]
  }
}

// ---------------- TN GEMM: C[M=2048][N] = A[M][K] * B[N][K]^T ----------------
// Tile 128 x BN (BN = WN*32), BK=64, 4 waves (2x2), 2-buffer ring + counted
// vmcnt + fenced raw barriers. Coalesced staging map (R20): chunk c ->
// r=(c>>3)&15, kq=c&7 fastest; source col pre-swizzled kq^(r&7); ds_read
// applies the same XOR. XCD map: 8bm x 4bn rectangle per XCD. grid = 256.
template <int WN, int OUTBF>
__global__ __launch_bounds__(256) void gemm_tn(const u16* __restrict__ A,
                                               const u16* __restrict__ B,
                                               void* __restrict__ Cv,
                                               int N, int K) {
  constexpr int BN = WN * 32;
  __shared__ u16 As[2][128 * 64];   // 2 x 16 KB
  __shared__ u16 Bs[2][BN * 64];    // 2 x BN/8 KB
  const int tid = threadIdx.x;
  const int w = tid >> 6, l = tid & 63;
  const int lin = blockIdx.x;
  const int xcd = lin & 7, pos = lin >> 3;
  const int bm = ((xcd & 1) << 3) + (pos & 7);
  const int bn = ((xcd >> 1) << 2) + (pos >> 3);
  const int wr = w >> 1, wc = w & 1;

  f32x4 acc[4][WN] = {};

  int rowA[4], colA[4], ldsA[4];
#pragma unroll
  for (int g = 0; g < 4; ++g) {
    int c = g * 256 + w * 64 + l;
    rowA[g] = ((c >> 7) << 4) + ((c >> 3) & 15);
    colA[g] = ((c & 7) ^ ((c >> 3) & 7)) * 8;
    ldsA[g] = (g * 256 + w * 64) * 8;
  }
  int rowB[WN], colB[WN], ldsB[WN];
#pragma unroll
  for (int g = 0; g < WN; ++g) {
    int c = g * 256 + w * 64 + l;
    rowB[g] = ((c >> 7) << 4) + ((c >> 3) & 15);
    colB[g] = ((c & 7) ^ ((c >> 3) & 7)) * 8;
    ldsB[g] = (g * 256 + w * 64) * 8;
  }
  const u16* Arow = A + (size_t)(bm * 128) * K;
  const u16* Brow = B + (size_t)(bn * BN) * K;

  auto stage = [&](int buf, int k0) {
#pragma unroll
    for (int g = 0; g < 4; ++g)
      gload_lds16(Arow + (size_t)rowA[g] * K + k0 + colA[g], &As[buf][ldsA[g]]);
#pragma unroll
    for (int g = 0; g < WN; ++g)
      gload_lds16(Brow + (size_t)rowB[g] * K + k0 + colB[g], &Bs[buf][ldsB[g]]);
  };

  const int nk = K >> 6;
  stage(0, 0);

  for (int k = 0; k < nk; ++k) {
    CFENCE(); __builtin_amdgcn_s_barrier(); CFENCE();  // compute k-1 done by all
    if (k + 1 < nk) {
      stage((k + 1) & 1, (k + 1) * 64);
      if constexpr (WN == 6) asm volatile("s_waitcnt vmcnt(10)" ::: "memory");
      else                   asm volatile("s_waitcnt vmcnt(8)" ::: "memory");
    } else {
      asm volatile("s_waitcnt vmcnt(0)" ::: "memory");
    }
    CFENCE(); __builtin_amdgcn_s_barrier(); CFENCE();  // tile k visible to all
    const int cur = k & 1;
#pragma unroll
    for (int ks = 0; ks < 2; ++ks) {
      const int xq = ((ks * 4 + (l >> 4)) ^ (l & 7)) * 8;
      const int rbase = (l & 15) * 64 + xq;
      bf16x8 af[4], bfr[WN];
#pragma unroll
      for (int mi = 0; mi < 4; ++mi)
        af[mi] = *(const bf16x8*)&As[cur][(wr * 4 + mi) * 1024 + rbase];
#pragma unroll
      for (int ni = 0; ni < WN; ++ni)
        bfr[ni] = *(const bf16x8*)&Bs[cur][(wc * WN + ni) * 1024 + rbase];
#pragma unroll
      for (int mi = 0; mi < 4; ++mi)
#pragma unroll
        for (int ni = 0; ni < WN; ++ni)
          acc[mi][ni] = __builtin_amdgcn_mfma_f32_16x16x32_bf16(af[mi], bfr[ni],
                                                                acc[mi][ni], 0, 0, 0);
    }
  }
  const int cr = (l >> 4) * 4, cc = l & 15;
#pragma unroll
  for (int mi = 0; mi < 4; ++mi) {
    int row0 = bm * 128 + wr * 64 + mi * 16 + cr;
#pragma unroll
    for (int ni = 0; ni < WN; ++ni) {
      int col = bn * BN + wc * (WN * 16) + ni * 16 + cc;
      if constexpr (OUTBF) {
        u16* C = (u16*)Cv;
#pragma unroll
        for (int i = 0; i < 4; ++i)
          C[(size_t)(row0 + i) * N + col] = f2bf(acc[mi][ni][i]);
      } else {
        float* C = (float*)Cv;
#pragma unroll
        for (int i = 0; i < 4; ++i)
          C[(size_t)(row0 + i) * N + col] = acc[mi][ni][i];
      }
    }
  }
}

// ---------------- RoPE/RMSNorm + V-transpose (bf16 qkv input) ----------------
// V output layout: Vt[kv][kb=64][d=64][k=32]  (4KB contiguous per block)
__global__ __launch_bounds__(256) void rope_vtrans(const u16* __restrict__ qkv,
                                                   const float* __restrict__ qw,
                                                   const float* __restrict__ kw,
                                                   u16* __restrict__ Qo,
                                                   u16* __restrict__ Ko,
                                                   u16* __restrict__ Vt) {
  __shared__ float tile[32][65];
  const int b = blockIdx.x, tid = threadIdx.x;
  if (b < 20480) {
    int s = (b & 511) * 4 + (tid >> 6);
    int hh = b >> 9;
    int d = tid & 63;
    bool isq = hh < 32;
    int col = isq ? hh * 64 + d : 2048 + (hh - 32) * 64 + d;
    float x = bf2f(qkv[(size_t)s * QKVN + col]);
    int i = d & 31;
    float inv_freq = exp2f(-(float)i * (13.287712379549449f / 32.0f));
    float ang = (float)s * inv_freq;
    float sn, cs;
    __sincosf(ang, &sn, &cs);
    float partner = __shfl_xor(x, 32, 64);
    float y = (d < 32) ? (x * cs - partner * sn) : (x * cs + partner * sn);
    float ss = y * y;
#pragma unroll
    for (int off = 32; off; off >>= 1) ss += __shfl_xor(ss, off, 64);
    float r = rsqrtf(ss * (1.0f / 64.0f) + 1e-6f);
    float o = y * r * (isq ? qw[d] : kw[d]);
    if (isq) Qo[((size_t)hh * SLEN + s) * 64 + d] = f2bf(o * QSCALE);
    else     Ko[((size_t)(hh - 32) * SLEN + s) * 64 + d] = f2bf(o);
  } else {
    int t = b - 20480;
    int kv = t >> 6;
    int s0 = (t & 63) * 32;
    int d = tid & 63, r4 = tid >> 6;
#pragma unroll
    for (int i = 0; i < 32; i += 4)
      tile[i + r4][d] = bf2f(qkv[(size_t)(s0 + i + r4) * QKVN + 2560 + kv * 64 + d]);
    __syncthreads();
    int dr = tid >> 2, sc = (tid & 3) * 8;
    u16x8 o;
#pragma unroll
    for (int j = 0; j < 8; ++j) o[j] = f2bf(tile[sc + j][dr]);
    *(u16x8*)(Vt + (((size_t)kv * 64 + (s0 >> 5)) * 64 + dr) * 32 + sc) = o;
  }
}

// ---------------- flash attention: 2048 single-tile blocks, refill ----------
// grid 2048: xcd = lin&7, pos = lin>>3 (0..255); head h = xcd*4 + (pos&3)
// (one kv head/XCD), qt = 63 - (pos>>2) (longest dispatched first -> HW
// refills CU slots as short blocks retire). 4-wave in-block split-K.
// bf16 LDS partials (16KB) keep the footprint refill-friendly.
// Fixed-scale softmax: p = v_exp(s); masked -> 0. Combine = sum(acc)/sum(l).
__global__ __launch_bounds__(256) void attn_fused(const u16* __restrict__ Q,
                                                  const u16* __restrict__ Kh,
                                                  const u16* __restrict__ Vt,
                                                  const uint32_t* __restrict__ mbits,
                                                  u16* __restrict__ Aout) {
  __shared__ u16 accS[4 * 32 * 64];    // 16 KB (bf16 partials)
  __shared__ float lS[4 * 32];         // 0.5 KB
  const int w = threadIdx.x >> 6, l = threadIdx.x & 63;
  const int lin = blockIdx.x;
  const int xcd = lin & 7, pos = lin >> 3;
  const int h = xcd * 4 + (pos & 3);   // 4 heads/XCD = one kv head
  const int qt = 63 - (pos >> 2);      // longest blocks dispatched first
  const int q0 = qt * 32;
  const int nkb = qt + 1;
  const int hkv = h >> 2;
  const bool web = (h >= 16);
  const int l31 = l & 31, hi = l >> 5;
  const int qrel = l31 - 4 * hi;  // diag-block causal: keep iff ki <= qrel

  const u16* Kp = Kh + ((size_t)hkv * SLEN + l31) * 64 + hi * 8;
  const u16* Vbase = Vt + (size_t)hkv * 64 * SLEN;   // blocked: +kb*2048
  const int voff = l31 * 32 + hi * 8;
  const uint32_t* mrowT = mbits + q0 + l31;          // transposed: +kword*2048

  const u16* Qp = Q + ((size_t)h * SLEN + q0 + l31) * 64 + hi * 8;
  bf16x8 qf0 = *(const bf16x8*)(Qp);
  bf16x8 qf1 = *(const bf16x8*)(Qp + 16);
  bf16x8 qf2 = *(const bf16x8*)(Qp + 32);
  bf16x8 qf3 = *(const bf16x8*)(Qp + 48);

  f32x16 acc0 = {}, acc1 = {};   // O^T[d][q]
  float llh = 0.f;               // this half's sum; combined at end

#define LOADSET(P, kbn)                                                         \
  do {                                                                          \
    const u16* knp_ = Kp + (size_t)(kbn) * 2048;                                \
    P##k0 = *(const bf16x8*)(knp_);                                             \
    P##k1 = *(const bf16x8*)(knp_ + 16);                                        \
    P##k2 = *(const bf16x8*)(knp_ + 32);                                        \
    P##k3 = *(const bf16x8*)(knp_ + 48);                                        \
    const u16* vnp_ = Vbase + (size_t)(kbn) * 2048 + voff;                      \
    P##v0 = *(const bf16x8*)(vnp_);                                             \
    P##v1 = *(const bf16x8*)(vnp_ + 16);                                        \
    P##v2 = *(const bf16x8*)(vnp_ + 1024);                                      \
    P##v3 = *(const bf16x8*)(vnp_ + 1024 + 16);                                 \
    if (web) P##m = mrowT[(size_t)(kbn) * 2048];                                \
  } while (0)

#define COMPUTE(P, kbv)                                                         \
  do {                                                                          \
    const int kb_ = (kbv);                                                      \
    __builtin_amdgcn_s_setprio(1);                                              \
    f32x16 s = {};                                                              \
    s = __builtin_amdgcn_mfma_f32_32x32x16_bf16(P##k0, qf0, s, 0, 0, 0);        \
    s = __builtin_amdgcn_mfma_f32_32x32x16_bf16(P##k1, qf1, s, 0, 0, 0);        \
    s = __builtin_amdgcn_mfma_f32_32x32x16_bf16(P##k2, qf2, s, 0, 0, 0);        \
    s = __builtin_amdgcn_mfma_f32_32x32x16_bf16(P##k3, qf3, s, 0, 0, 0);        \
    __builtin_amdgcn_s_setprio(0);                                              \
    if (web) {                                                                  \
      uint32_t word = P##m >> (hi * 4);                                         \
      if (kb_ == qt) {                                                          \
        _Pragma("unroll")                                                       \
        for (int r = 0; r < 16; ++r) {                                          \
          const int ki = (r & 3) + 8 * (r >> 2);                                \
          bool keep = ((word >> ki) & 1u) && (ki <= qrel);                      \
          s[r] = keep ? s[r] : -1e9f;                                           \
        }                                                                       \
      } else {                                                                  \
        _Pragma("unroll")                                                       \
        for (int r = 0; r < 16; ++r) {                                          \
          const int ki = (r & 3) + 8 * (r >> 2);                                \
          s[r] = ((word >> ki) & 1u) ? s[r] : -1e9f;                            \
        }                                                                       \
      }                                                                         \
    } else if (kb_ == qt) {                                                     \
      _Pragma("unroll")                                                         \
      for (int r = 0; r < 16; ++r) {                                            \
        const int ki = (r & 3) + 8 * (r >> 2);                                  \
        s[r] = (ki <= qrel) ? s[r] : -1e9f;                                     \
      }                                                                         \
    }                                                                           \
    f32x16 p;                                                                   \
    _Pragma("unroll")                                                           \
    for (int r = 0; r < 16; ++r) p[r] = fast_exp2(s[r]);                        \
    float rs = ((p[0] + p[1]) + (p[2] + p[3])) + ((p[4] + p[5]) + (p[6] + p[7]))\
             + ((p[8] + p[9]) + (p[10] + p[11]))                                \
             + ((p[12] + p[13]) + (p[14] + p[15]));                             \
    llh += rs;                                                                  \
    uint32_t a0 = cvtpk_bf16(p[0], p[1]),   b0 = cvtpk_bf16(p[2], p[3]);        \
    uint32_t c0 = cvtpk_bf16(p[4], p[5]),   d0 = cvtpk_bf16(p[6], p[7]);        \
    uint32_t a1 = cvtpk_bf16(p[8], p[9]),   b1 = cvtpk_bf16(p[10], p[11]);      \
    uint32_t c1 = cvtpk_bf16(p[12], p[13]), d1 = cvtpk_bf16(p[14], p[15]);      \
    auto r0 = __builtin_amdgcn_permlane32_swap(a0, c0, false, false);           \
    auto r1 = __builtin_amdgcn_permlane32_swap(b0, d0, false, false);           \
    auto r2 = __builtin_amdgcn_permlane32_swap(a1, c1, false, false);           \
    auto r3 = __builtin_amdgcn_permlane32_swap(b1, d1, false, false);           \
    union { uint32_t wv[4]; bf16x8 v; } pf0u, pf1u;                             \
    pf0u.wv[0] = r0[0]; pf0u.wv[1] = r1[0]; pf0u.wv[2] = r0[1]; pf0u.wv[3] = r1[1]; \
    pf1u.wv[0] = r2[0]; pf1u.wv[1] = r3[0]; pf1u.wv[2] = r2[1]; pf1u.wv[3] = r3[1]; \
    __builtin_amdgcn_s_setprio(1);                                              \
    acc0 = __builtin_amdgcn_mfma_f32_32x32x16_bf16(P##v0, pf0u.v, acc0, 0, 0, 0); \
    acc0 = __builtin_amdgcn_mfma_f32_32x32x16_bf16(P##v1, pf1u.v, acc0, 0, 0, 0); \
    acc1 = __builtin_amdgcn_mfma_f32_32x32x16_bf16(P##v2, pf0u.v, acc1, 0, 0, 0); \
    acc1 = __builtin_amdgcn_mfma_f32_32x32x16_bf16(P##v3, pf1u.v, acc1, 0, 0, 0); \
    __builtin_amdgcn_s_setprio(0);                                              \
  } while (0)

  if (w < nkb) {
    bf16x8 Ak0, Ak1, Ak2, Ak3, Av0, Av1, Av2, Av3;
    bf16x8 Bk0, Bk1, Bk2, Bk3, Bv0, Bv1, Bv2, Bv3;
    uint32_t Am = 0, Bm = 0;
    int kb = w;
    LOADSET(A, kb);
    while (true) {
      if (kb + 4 < nkb) LOADSET(B, kb + 4);
      COMPUTE(A, kb);
      kb += 4;
      if (kb >= nkb) break;
      if (kb + 4 < nkb) LOADSET(A, kb + 4);
      COMPUTE(B, kb);
      kb += 4;
      if (kb >= nkb) break;
    }
  }
#undef LOADSET
#undef COMPUTE

  const float ll = xhalf_sum(llh);  // combine halves once
  // ---- stash per-wave state in LDS (bf16 acc + f32 l) ----
  if (hi == 0) lS[w * 32 + l31] = ll;
  u16* wbase = accS + w * 2048 + (l31 << 6);
  const int sw = (l31 & 15) << 2;  // swizzle: d ^= sw
#pragma unroll
  for (int tt = 0; tt < 4; ++tt) {
    int dA = (8 * tt + 4 * hi) ^ sw;
    int dB = (32 + 8 * tt + 4 * hi) ^ sw;
    uint2 pA, pB;
    pA.x = cvtpk_bf16(acc0[4 * tt], acc0[4 * tt + 1]);
    pA.y = cvtpk_bf16(acc0[4 * tt + 2], acc0[4 * tt + 3]);
    pB.x = cvtpk_bf16(acc1[4 * tt], acc1[4 * tt + 1]);
    pB.y = cvtpk_bf16(acc1[4 * tt + 2], acc1[4 * tt + 3]);
    *(uint2*)(wbase + dA) = pA;
    *(uint2*)(wbase + dB) = pB;
  }
  __syncthreads();
  // ---- combine: thread -> (q = tid&31, d = (tid>>5)*8); plain sum / L ----
  const int q = threadIdx.x & 31;
  const int dd = (threadIdx.x >> 5) * 8;
  float L = (lS[q] + lS[32 + q]) + (lS[64 + q] + lS[96 + q]);
  const int offA = (q << 6) + (dd ^ ((q & 15) << 2));
  const int offB = offA ^ 4;
  float o[8] = {};
#pragma unroll
  for (int ww = 0; ww < 4; ++ww) {
    const u16* pbase = accS + ww * 2048;
    uint2 xa = *(const uint2*)(pbase + offA);
    uint2 xb = *(const uint2*)(pbase + offB);
    o[0] += bf2f((u16)(xa.x & 0xffffu)); o[1] += bf2f((u16)(xa.x >> 16));
    o[2] += bf2f((u16)(xa.y & 0xffffu)); o[3] += bf2f((u16)(xa.y >> 16));
    o[4] += bf2f((u16)(xb.x & 0xffffu)); o[5] += bf2f((u16)(xb.x >> 16));
    o[6] += bf2f((u16)(xb.y & 0xffffu)); o[7] += bf2f((u16)(xb.y >> 16));
  }
  const float invL = 1.0f / L;
  uint4 pk;
  pk.x = cvtpk_bf16(o[0] * invL, o[1] * invL);
  pk.y = cvtpk_bf16(o[2] * invL, o[3] * invL);
  pk.z = cvtpk_bf16(o[4] * invL, o[5] * invL);
  pk.w = cvtpk_bf16(o[6] * invL, o[7] * invL);
  *(uint4*)(Aout + (size_t)(q0 + q) * HIDDEN + h * 64 + dd) = pk;
}

// ---------------- launch ----------------

extern "C" void kernel_launch(void* const* d_in, const int* in_sizes, int n_in,
                              void* d_out, int out_size, void* d_ws, size_t ws_size,
                              hipStream_t stream) {
  const float* hidden  = (const float*)d_in[0];
  const float* webmask = (const float*)d_in[3];
  const float* Wq = (const float*)d_in[4];
  const float* Wk = (const float*)d_in[5];
  const float* Wv = (const float*)d_in[6];
  const float* Wo = (const float*)d_in[7];
  const float* qlnw = (const float*)d_in[8];
  const float* klnw = (const float*)d_in[9];
  float* out = (float*)d_out;

  char* ws = (char*)d_ws;
  u16*      hbf  = (u16*)(ws);                         // 8 MB  hidden bf16
  u16*      Wcat = (u16*)(ws + (8u << 20));            // 12 MB QKV weights^T
  u16*      Wot  = (u16*)(ws + (20u << 20));           // 8 MB  Wo^T
  u16*      qkv  = (u16*)(ws + (28u << 20));           // 12 MB QKV bf16
  u16*      Qh   = (u16*)(ws + (52u << 20));           // 8 MB  Q' (pre-scaled)
  u16*      Kh   = (u16*)(ws + (60u << 20));           // 2 MB  K'
  u16*      Vt   = (u16*)(ws + (62u << 20));           // 2 MB  V^T (blocked)
  u16*      Ao   = (u16*)(ws + (64u << 20));           // 8 MB  attn out bf16
  uint32_t* mb   = (uint32_t*)(ws + (72u << 20));      // 0.5 MB web mask bits (T)

  prep_all<<<14848, 256, 0, stream>>>(hidden, hbf, Wq, Wk, Wv, Wo, Wcat, Wot,
                                      webmask, mb);
  gemm_tn<6, 1><<<256, 256, 0, stream>>>(hbf, Wcat, qkv, QKVN, HIDDEN);  // bf16 C
  rope_vtrans<<<20992, 256, 0, stream>>>(qkv, qlnw, klnw, Qh, Kh, Vt);
  attn_fused<<<2048, 256, 0, stream>>>(Qh, Kh, Vt, mb, Ao);
  gemm_tn<4, 0><<<256, 256, 0, stream>>>(Ao, Wot, out, HIDDEN, HIDDEN);  // fp32 C
}

// Round 29
// 182.008 us; speedup vs baseline: 1.0178x; 1.0113x over previous
//
#include <hip/hip_runtime.h>
#include <stdint.h>

// WebAttention fused block for MI355X (gfx950).
// R29: REVERT to R26 (best measured: 181.7 us). R27 (ballot mask pack) and
//      R28 (refill grid + bf16 partials) both measured null-to-worse; per
//      post-mortem discipline the session locks in the best-known state.
// Stack: R20 coalesced GEMM staging + XOR swizzle; R19 8x4 XCD rectangles;
//        R18 bf16 QKV C; R22 blocked V / transposed mask; R23 fixed-scale
//        softmax; R24 raw v_exp_f32; R25 setprio; R26 ping-pong reg sets;
//        R21 paired-tile single-dispatch attention.

typedef unsigned short u16;
typedef unsigned short u16x4 __attribute__((ext_vector_type(4)));
typedef unsigned short u16x8 __attribute__((ext_vector_type(8)));
typedef __bf16 bf16x8 __attribute__((ext_vector_type(8)));
typedef float f32x4 __attribute__((ext_vector_type(4)));
typedef float f32x16 __attribute__((ext_vector_type(16)));

#define SLEN 2048
#define HIDDEN 2048
#define QKVN 3072   // 2048 Q + 512 K + 512 V
// Q pre-scale: 1/sqrt(64) * log2(e)  -> scores land in exp2 domain
#define QSCALE 0.18033688011112042f

#define CFENCE() asm volatile("" ::: "memory")

__device__ __forceinline__ u16 f2bf(float x) {  // RNE, matches numpy/JAX
  uint32_t u = __float_as_uint(x);
  return (u16)((u + 0x7FFFu + ((u >> 16) & 1u)) >> 16);
}

__device__ __forceinline__ float bf2f(u16 x) {
  return __uint_as_float((uint32_t)x << 16);
}

__device__ __forceinline__ uint32_t cvtpk_bf16(float lo, float hi) {
  uint32_t r;
  asm("v_cvt_pk_bf16_f32 %0, %1, %2" : "=v"(r) : "v"(lo), "v"(hi));
  return r;
}

// raw hardware exp2 (D = 2^S0). VALU deps are HW-interlocked on CDNA.
__device__ __forceinline__ float fast_exp2(float x) {
  float r;
  asm("v_exp_f32 %0, %1" : "=v"(r) : "v"(x));
  return r;
}

// Cross-half (lane ^ 32) sum: {r[0],r[1]} = {self, partner} as a set.
__device__ __forceinline__ float xhalf_sum(float x) {
  auto r = __builtin_amdgcn_permlane32_swap(__float_as_uint(x), __float_as_uint(x),
                                            false, false);
  return __uint_as_float(r[0]) + __uint_as_float(r[1]);
}

__device__ __forceinline__ void gload_lds16(const void* g, void* l) {
  __builtin_amdgcn_global_load_lds(
      (const __attribute__((address_space(1))) void*)g,
      (__attribute__((address_space(3))) void*)l, 16, 0, 0);
}

// ---------------- prep_all: cvt + 4 transposes + pack_mask in one kernel -----
__device__ __forceinline__ void transpose_tile(const float* in, int ldin,
                                               u16* out, int ldout,
                                               int k0, int n0, int tid,
                                               float (*tile)[33]) {
  int x = tid & 31, y = tid >> 5;  // y in 0..7
#pragma unroll
  for (int i = 0; i < 32; i += 8)
    tile[y + i][x] = in[(size_t)(k0 + y + i) * ldin + n0 + x];
  __syncthreads();
#pragma unroll
  for (int i = 0; i < 32; i += 8)
    out[(size_t)(n0 + y + i) * ldout + k0 + x] = f2bf(tile[x][y + i]);
}

__global__ __launch_bounds__(256) void prep_all(const float* __restrict__ hidden,
                                                u16* __restrict__ hbf,
                                                const float* __restrict__ Wq,
                                                const float* __restrict__ Wk,
                                                const float* __restrict__ Wv,
                                                const float* __restrict__ Wo,
                                                u16* __restrict__ Wcat,
                                                u16* __restrict__ Wot,
                                                const float* __restrict__ webmask,
                                                uint32_t* __restrict__ mbits) {
  __shared__ float tile[32][33];
  const int b = blockIdx.x, tid = threadIdx.x;
  if (b < 4096) {
    int idx = (b * 256 + tid) * 4;
    float4 v = *(const float4*)(hidden + idx);
    u16x4 o;
    o[0] = f2bf(v.x); o[1] = f2bf(v.y); o[2] = f2bf(v.z); o[3] = f2bf(v.w);
    *(u16x4*)(hbf + idx) = o;
  } else if (b < 8192) {
    int t = b - 4096;
    transpose_tile(Wq, 2048, Wcat, 2048, (t & 63) * 32, (t >> 6) * 32, tid, tile);
  } else if (b < 9216) {
    int t = b - 8192;
    transpose_tile(Wk, 512, Wcat + (size_t)2048 * 2048, 2048,
                   (t & 63) * 32, (t >> 6) * 32, tid, tile);
  } else if (b < 10240) {
    int t = b - 9216;
    transpose_tile(Wv, 512, Wcat + (size_t)2560 * 2048, 2048,
                   (t & 63) * 32, (t >> 6) * 32, tid, tile);
  } else if (b < 14336) {
    int t = b - 10240;
    transpose_tile(Wo, 2048, Wot, 2048, (t & 63) * 32, (t >> 6) * 32, tid, tile);
  } else {
    int w = (b - 14336) * 256 + tid;  // 2048*64 words; s = w>>6, kword = w&63
    const float* p = webmask + (size_t)w * 32;
    uint32_t bits = 0;
#pragma unroll
    for (int j = 0; j < 32; ++j) bits |= (p[j] > -0.5f ? 1u : 0u) << j;
    mbits[(size_t)(w & 63) * 2048 + (w >> 6)] = bits;   // TRANSPOSED [kword][s]
  }
}

// ---------------- TN GEMM: C[M=2048][N] = A[M][K] * B[N][K]^T ----------------
// Tile 128 x BN (BN = WN*32), BK=64, 4 waves (2x2), 2-buffer ring + counted
// vmcnt + fenced raw barriers. Coalesced staging map (R20): chunk c ->
// r=(c>>3)&15, kq=c&7 fastest; source col pre-swizzled kq^(r&7); ds_read
// applies the same XOR. XCD map: 8bm x 4bn rectangle per XCD. grid = 256.
template <int WN, int OUTBF>
__global__ __launch_bounds__(256) void gemm_tn(const u16* __restrict__ A,
                                               const u16* __restrict__ B,
                                               void* __restrict__ Cv,
                                               int N, int K) {
  constexpr int BN = WN * 32;
  __shared__ u16 As[2][128 * 64];   // 2 x 16 KB
  __shared__ u16 Bs[2][BN * 64];    // 2 x BN/8 KB
  const int tid = threadIdx.x;
  const int w = tid >> 6, l = tid & 63;
  const int lin = blockIdx.x;
  const int xcd = lin & 7, pos = lin >> 3;
  const int bm = ((xcd & 1) << 3) + (pos & 7);
  const int bn = ((xcd >> 1) << 2) + (pos >> 3);
  const int wr = w >> 1, wc = w & 1;

  f32x4 acc[4][WN] = {};

  int rowA[4], colA[4], ldsA[4];
#pragma unroll
  for (int g = 0; g < 4; ++g) {
    int c = g * 256 + w * 64 + l;
    rowA[g] = ((c >> 7) << 4) + ((c >> 3) & 15);
    colA[g] = ((c & 7) ^ ((c >> 3) & 7)) * 8;
    ldsA[g] = (g * 256 + w * 64) * 8;
  }
  int rowB[WN], colB[WN], ldsB[WN];
#pragma unroll
  for (int g = 0; g < WN; ++g) {
    int c = g * 256 + w * 64 + l;
    rowB[g] = ((c >> 7) << 4) + ((c >> 3) & 15);
    colB[g] = ((c & 7) ^ ((c >> 3) & 7)) * 8;
    ldsB[g] = (g * 256 + w * 64) * 8;
  }
  const u16* Arow = A + (size_t)(bm * 128) * K;
  const u16* Brow = B + (size_t)(bn * BN) * K;

  auto stage = [&](int buf, int k0) {
#pragma unroll
    for (int g = 0; g < 4; ++g)
      gload_lds16(Arow + (size_t)rowA[g] * K + k0 + colA[g], &As[buf][ldsA[g]]);
#pragma unroll
    for (int g = 0; g < WN; ++g)
      gload_lds16(Brow + (size_t)rowB[g] * K + k0 + colB[g], &Bs[buf][ldsB[g]]);
  };

  const int nk = K >> 6;
  stage(0, 0);

  for (int k = 0; k < nk; ++k) {
    CFENCE(); __builtin_amdgcn_s_barrier(); CFENCE();  // compute k-1 done by all
    if (k + 1 < nk) {
      stage((k + 1) & 1, (k + 1) * 64);
      if constexpr (WN == 6) asm volatile("s_waitcnt vmcnt(10)" ::: "memory");
      else                   asm volatile("s_waitcnt vmcnt(8)" ::: "memory");
    } else {
      asm volatile("s_waitcnt vmcnt(0)" ::: "memory");
    }
    CFENCE(); __builtin_amdgcn_s_barrier(); CFENCE();  // tile k visible to all
    const int cur = k & 1;
#pragma unroll
    for (int ks = 0; ks < 2; ++ks) {
      const int xq = ((ks * 4 + (l >> 4)) ^ (l & 7)) * 8;
      const int rbase = (l & 15) * 64 + xq;
      bf16x8 af[4], bfr[WN];
#pragma unroll
      for (int mi = 0; mi < 4; ++mi)
        af[mi] = *(const bf16x8*)&As[cur][(wr * 4 + mi) * 1024 + rbase];
#pragma unroll
      for (int ni = 0; ni < WN; ++ni)
        bfr[ni] = *(const bf16x8*)&Bs[cur][(wc * WN + ni) * 1024 + rbase];
#pragma unroll
      for (int mi = 0; mi < 4; ++mi)
#pragma unroll
        for (int ni = 0; ni < WN; ++ni)
          acc[mi][ni] = __builtin_amdgcn_mfma_f32_16x16x32_bf16(af[mi], bfr[ni],
                                                                acc[mi][ni], 0, 0, 0);
    }
  }
  const int cr = (l >> 4) * 4, cc = l & 15;
#pragma unroll
  for (int mi = 0; mi < 4; ++mi) {
    int row0 = bm * 128 + wr * 64 + mi * 16 + cr;
#pragma unroll
    for (int ni = 0; ni < WN; ++ni) {
      int col = bn * BN + wc * (WN * 16) + ni * 16 + cc;
      if constexpr (OUTBF) {
        u16* C = (u16*)Cv;
#pragma unroll
        for (int i = 0; i < 4; ++i)
          C[(size_t)(row0 + i) * N + col] = f2bf(acc[mi][ni][i]);
      } else {
        float* C = (float*)Cv;
#pragma unroll
        for (int i = 0; i < 4; ++i)
          C[(size_t)(row0 + i) * N + col] = acc[mi][ni][i];
      }
    }
  }
}

// ---------------- RoPE/RMSNorm + V-transpose (bf16 qkv input) ----------------
// V output layout: Vt[kv][kb=64][d=64][k=32]  (4KB contiguous per block)
__global__ __launch_bounds__(256) void rope_vtrans(const u16* __restrict__ qkv,
                                                   const float* __restrict__ qw,
                                                   const float* __restrict__ kw,
                                                   u16* __restrict__ Qo,
                                                   u16* __restrict__ Ko,
                                                   u16* __restrict__ Vt) {
  __shared__ float tile[32][65];
  const int b = blockIdx.x, tid = threadIdx.x;
  if (b < 20480) {
    int s = (b & 511) * 4 + (tid >> 6);
    int hh = b >> 9;
    int d = tid & 63;
    bool isq = hh < 32;
    int col = isq ? hh * 64 + d : 2048 + (hh - 32) * 64 + d;
    float x = bf2f(qkv[(size_t)s * QKVN + col]);
    int i = d & 31;
    float inv_freq = exp2f(-(float)i * (13.287712379549449f / 32.0f));
    float ang = (float)s * inv_freq;
    float sn, cs;
    __sincosf(ang, &sn, &cs);
    float partner = __shfl_xor(x, 32, 64);
    float y = (d < 32) ? (x * cs - partner * sn) : (x * cs + partner * sn);
    float ss = y * y;
#pragma unroll
    for (int off = 32; off; off >>= 1) ss += __shfl_xor(ss, off, 64);
    float r = rsqrtf(ss * (1.0f / 64.0f) + 1e-6f);
    float o = y * r * (isq ? qw[d] : kw[d]);
    if (isq) Qo[((size_t)hh * SLEN + s) * 64 + d] = f2bf(o * QSCALE);
    else     Ko[((size_t)(hh - 32) * SLEN + s) * 64 + d] = f2bf(o);
  } else {
    int t = b - 20480;
    int kv = t >> 6;
    int s0 = (t & 63) * 32;
    int d = tid & 63, r4 = tid >> 6;
#pragma unroll
    for (int i = 0; i < 32; i += 4)
      tile[i + r4][d] = bf2f(qkv[(size_t)(s0 + i + r4) * QKVN + 2560 + kv * 64 + d]);
    __syncthreads();
    int dr = tid >> 2, sc = (tid & 3) * 8;
    u16x8 o;
#pragma unroll
    for (int j = 0; j < 8; ++j) o[j] = f2bf(tile[sc + j][dr]);
    *(u16x8*)(Vt + (((size_t)kv * 64 + (s0 >> 5)) * 64 + dr) * 32 + sc) = o;
  }
}

// ---------------- flash attention: one dispatch, paired q-tiles ----------------
// grid 1024: head h = xcd*4 + (pos&3) (one kv head/XCD), pair j = pos>>2.
// Processes qt = 63-j then qt = j (LDS reused), 4-wave in-block split-K.
// Fixed-scale softmax: p = v_exp(s); masked -> 0. Combine = sum(acc)/sum(l).
// 2-stage ping-pong register sets (R26).
__global__ __launch_bounds__(256) void attn_fused(const u16* __restrict__ Q,
                                                  const u16* __restrict__ Kh,
                                                  const u16* __restrict__ Vt,
                                                  const uint32_t* __restrict__ mbits,
                                                  u16* __restrict__ Aout) {
  __shared__ float accS[4 * 32 * 64];  // 32 KB
  __shared__ float lS[4 * 32];         // 0.5 KB
  const int w = threadIdx.x >> 6, l = threadIdx.x & 63;
  const int lin = blockIdx.x;
  const int xcd = lin & 7, pos = lin >> 3;
  const int h = xcd * 4 + (pos & 3);   // 4 heads/XCD = one kv head
  const int j = pos >> 2;              // pair index 0..31
  const int hkv = h >> 2;
  const bool web = (h >= 16);
  const int l31 = l & 31, hi = l >> 5;
  const int qrel = l31 - 4 * hi;  // diag-block causal: keep iff ki <= qrel

  const u16* Kp = Kh + ((size_t)hkv * SLEN + l31) * 64 + hi * 8;
  const u16* Vbase = Vt + (size_t)hkv * 64 * SLEN;   // blocked: +kb*2048
  const int voff = l31 * 32 + hi * 8;

#define LOADSET(P, kbn)                                                         \
  do {                                                                          \
    const u16* knp_ = Kp + (size_t)(kbn) * 2048;                                \
    P##k0 = *(const bf16x8*)(knp_);                                             \
    P##k1 = *(const bf16x8*)(knp_ + 16);                                        \
    P##k2 = *(const bf16x8*)(knp_ + 32);                                        \
    P##k3 = *(const bf16x8*)(knp_ + 48);                                        \
    const u16* vnp_ = Vbase + (size_t)(kbn) * 2048 + voff;                      \
    P##v0 = *(const bf16x8*)(vnp_);                                             \
    P##v1 = *(const bf16x8*)(vnp_ + 16);                                        \
    P##v2 = *(const bf16x8*)(vnp_ + 1024);                                      \
    P##v3 = *(const bf16x8*)(vnp_ + 1024 + 16);                                 \
    if (web) P##m = mrowT[(size_t)(kbn) * 2048];                                \
  } while (0)

#define COMPUTE(P, kbv)                                                         \
  do {                                                                          \
    const int kb_ = (kbv);                                                      \
    __builtin_amdgcn_s_setprio(1);                                              \
    f32x16 s = {};                                                              \
    s = __builtin_amdgcn_mfma_f32_32x32x16_bf16(P##k0, qf0, s, 0, 0, 0);        \
    s = __builtin_amdgcn_mfma_f32_32x32x16_bf16(P##k1, qf1, s, 0, 0, 0);        \
    s = __builtin_amdgcn_mfma_f32_32x32x16_bf16(P##k2, qf2, s, 0, 0, 0);        \
    s = __builtin_amdgcn_mfma_f32_32x32x16_bf16(P##k3, qf3, s, 0, 0, 0);        \
    __builtin_amdgcn_s_setprio(0);                                              \
    if (web) {                                                                  \
      uint32_t word = P##m >> (hi * 4);                                         \
      if (kb_ == qt) {                                                          \
        _Pragma("unroll")                                                       \
        for (int r = 0; r < 16; ++r) {                                          \
          const int ki = (r & 3) + 8 * (r >> 2);                                \
          bool keep = ((word >> ki) & 1u) && (ki <= qrel);                      \
          s[r] = keep ? s[r] : -1e9f;                                           \
        }                                                                       \
      } else {                                                                  \
        _Pragma("unroll")                                                       \
        for (int r = 0; r < 16; ++r) {                                          \
          const int ki = (r & 3) + 8 * (r >> 2);                                \
          s[r] = ((word >> ki) & 1u) ? s[r] : -1e9f;                            \
        }                                                                       \
      }                                                                         \
    } else if (kb_ == qt) {                                                     \
      _Pragma("unroll")                                                         \
      for (int r = 0; r < 16; ++r) {                                            \
        const int ki = (r & 3) + 8 * (r >> 2);                                  \
        s[r] = (ki <= qrel) ? s[r] : -1e9f;                                     \
      }                                                                         \
    }                                                                           \
    f32x16 p;                                                                   \
    _Pragma("unroll")                                                           \
    for (int r = 0; r < 16; ++r) p[r] = fast_exp2(s[r]);                        \
    float rs = ((p[0] + p[1]) + (p[2] + p[3])) + ((p[4] + p[5]) + (p[6] + p[7]))\
             + ((p[8] + p[9]) + (p[10] + p[11]))                                \
             + ((p[12] + p[13]) + (p[14] + p[15]));                             \
    llh += rs;                                                                  \
    uint32_t a0 = cvtpk_bf16(p[0], p[1]),   b0 = cvtpk_bf16(p[2], p[3]);        \
    uint32_t c0 = cvtpk_bf16(p[4], p[5]),   d0 = cvtpk_bf16(p[6], p[7]);        \
    uint32_t a1 = cvtpk_bf16(p[8], p[9]),   b1 = cvtpk_bf16(p[10], p[11]);      \
    uint32_t c1 = cvtpk_bf16(p[12], p[13]), d1 = cvtpk_bf16(p[14], p[15]);      \
    auto r0 = __builtin_amdgcn_permlane32_swap(a0, c0, false, false);           \
    auto r1 = __builtin_amdgcn_permlane32_swap(b0, d0, false, false);           \
    auto r2 = __builtin_amdgcn_permlane32_swap(a1, c1, false, false);           \
    auto r3 = __builtin_amdgcn_permlane32_swap(b1, d1, false, false);           \
    union { uint32_t wv[4]; bf16x8 v; } pf0u, pf1u;                             \
    pf0u.wv[0] = r0[0]; pf0u.wv[1] = r1[0]; pf0u.wv[2] = r0[1]; pf0u.wv[3] = r1[1]; \
    pf1u.wv[0] = r2[0]; pf1u.wv[1] = r3[0]; pf1u.wv[2] = r2[1]; pf1u.wv[3] = r3[1]; \
    __builtin_amdgcn_s_setprio(1);                                              \
    acc0 = __builtin_amdgcn_mfma_f32_32x32x16_bf16(P##v0, pf0u.v, acc0, 0, 0, 0); \
    acc0 = __builtin_amdgcn_mfma_f32_32x32x16_bf16(P##v1, pf1u.v, acc0, 0, 0, 0); \
    acc1 = __builtin_amdgcn_mfma_f32_32x32x16_bf16(P##v2, pf0u.v, acc1, 0, 0, 0); \
    acc1 = __builtin_amdgcn_mfma_f32_32x32x16_bf16(P##v3, pf1u.v, acc1, 0, 0, 0); \
    __builtin_amdgcn_s_setprio(0);                                              \
  } while (0)

#pragma unroll
  for (int t = 0; t < 2; ++t) {
    const int qt = t == 0 ? (63 - j) : j;
    const int q0 = qt * 32;
    const int nkb = qt + 1;
    const uint32_t* mrowT = mbits + q0 + l31;        // transposed: +kword*2048

    const u16* Qp = Q + ((size_t)h * SLEN + q0 + l31) * 64 + hi * 8;
    bf16x8 qf0 = *(const bf16x8*)(Qp);
    bf16x8 qf1 = *(const bf16x8*)(Qp + 16);
    bf16x8 qf2 = *(const bf16x8*)(Qp + 32);
    bf16x8 qf3 = *(const bf16x8*)(Qp + 48);

    f32x16 acc0 = {}, acc1 = {};   // O^T[d][q]
    float llh = 0.f;               // this half's sum; combined at end

    if (w < nkb) {
      bf16x8 Ak0, Ak1, Ak2, Ak3, Av0, Av1, Av2, Av3;
      bf16x8 Bk0, Bk1, Bk2, Bk3, Bv0, Bv1, Bv2, Bv3;
      uint32_t Am = 0, Bm = 0;
      int kb = w;
      LOADSET(A, kb);
      while (true) {
        if (kb + 4 < nkb) LOADSET(B, kb + 4);
        COMPUTE(A, kb);
        kb += 4;
        if (kb >= nkb) break;
        if (kb + 4 < nkb) LOADSET(A, kb + 4);
        COMPUTE(B, kb);
        kb += 4;
        if (kb >= nkb) break;
      }
    }
    const float ll = xhalf_sum(llh);  // combine halves once
    // ---- stash per-wave state in LDS (raw acc + l) ----
    if (hi == 0) lS[w * 32 + l31] = ll;
    float* wbase = accS + w * 2048 + (l31 << 6);
    const int sw = (l31 & 15) << 2;  // swizzle: d ^= sw
#pragma unroll
    for (int tt = 0; tt < 4; ++tt) {
      int dA = (8 * tt + 4 * hi) ^ sw;
      int dB = (32 + 8 * tt + 4 * hi) ^ sw;
      float4 v0 = {acc0[4 * tt], acc0[4 * tt + 1], acc0[4 * tt + 2], acc0[4 * tt + 3]};
      float4 v1 = {acc1[4 * tt], acc1[4 * tt + 1], acc1[4 * tt + 2], acc1[4 * tt + 3]};
      *(float4*)(wbase + dA) = v0;
      *(float4*)(wbase + dB) = v1;
    }
    __syncthreads();
    // ---- combine: thread -> (q = tid&31, d = (tid>>5)*8); plain sum / L ----
    const int q = threadIdx.x & 31;
    const int dd = (threadIdx.x >> 5) * 8;
    float L = (lS[q] + lS[32 + q]) + (lS[64 + q] + lS[96 + q]);
    const int offA = (q << 6) + (dd ^ ((q & 15) << 2));
    const int offB = offA ^ 4;
    float o[8];
    {
      float4 xa = *(float4*)(accS + offA);
      float4 xb = *(float4*)(accS + offB);
      o[0] = xa.x; o[1] = xa.y; o[2] = xa.z; o[3] = xa.w;
      o[4] = xb.x; o[5] = xb.y; o[6] = xb.z; o[7] = xb.w;
    }
#pragma unroll
    for (int ww = 1; ww < 4; ++ww) {
      float4 xa = *(float4*)(accS + ww * 2048 + offA);
      float4 xb = *(float4*)(accS + ww * 2048 + offB);
      o[0] += xa.x; o[1] += xa.y; o[2] += xa.z; o[3] += xa.w;
      o[4] += xb.x; o[5] += xb.y; o[6] += xb.z; o[7] += xb.w;
    }
    const float invL = 1.0f / L;
    uint4 pk;
    pk.x = cvtpk_bf16(o[0] * invL, o[1] * invL);
    pk.y = cvtpk_bf16(o[2] * invL, o[3] * invL);
    pk.z = cvtpk_bf16(o[4] * invL, o[5] * invL);
    pk.w = cvtpk_bf16(o[6] * invL, o[7] * invL);
    *(uint4*)(Aout + (size_t)(q0 + q) * HIDDEN + h * 64 + dd) = pk;
    __syncthreads();  // accS/lS reads done before next tile overwrites
  }
#undef LOADSET
#undef COMPUTE
}

// ---------------- launch ----------------

extern "C" void kernel_launch(void* const* d_in, const int* in_sizes, int n_in,
                              void* d_out, int out_size, void* d_ws, size_t ws_size,
                              hipStream_t stream) {
  const float* hidden  = (const float*)d_in[0];
  const float* webmask = (const float*)d_in[3];
  const float* Wq = (const float*)d_in[4];
  const float* Wk = (const float*)d_in[5];
  const float* Wv = (const float*)d_in[6];
  const float* Wo = (const float*)d_in[7];
  const float* qlnw = (const float*)d_in[8];
  const float* klnw = (const float*)d_in[9];
  float* out = (float*)d_out;

  char* ws = (char*)d_ws;
  u16*      hbf  = (u16*)(ws);                         // 8 MB  hidden bf16
  u16*      Wcat = (u16*)(ws + (8u << 20));            // 12 MB QKV weights^T
  u16*      Wot  = (u16*)(ws + (20u << 20));           // 8 MB  Wo^T
  u16*      qkv  = (u16*)(ws + (28u << 20));           // 12 MB QKV bf16
  u16*      Qh   = (u16*)(ws + (52u << 20));           // 8 MB  Q' (pre-scaled)
  u16*      Kh   = (u16*)(ws + (60u << 20));           // 2 MB  K'
  u16*      Vt   = (u16*)(ws + (62u << 20));           // 2 MB  V^T (blocked)
  u16*      Ao   = (u16*)(ws + (64u << 20));           // 8 MB  attn out bf16
  uint32_t* mb   = (uint32_t*)(ws + (72u << 20));      // 0.5 MB web mask bits (T)

  prep_all<<<14848, 256, 0, stream>>>(hidden, hbf, Wq, Wk, Wv, Wo, Wcat, Wot,
                                      webmask, mb);
  gemm_tn<6, 1><<<256, 256, 0, stream>>>(hbf, Wcat, qkv, QKVN, HIDDEN);  // bf16 C
  rope_vtrans<<<20992, 256, 0, stream>>>(qkv, qlnw, klnw, Qh, Kh, Vt);
  attn_fused<<<1024, 256, 0, stream>>>(Qh, Kh, Vt, mb, Ao);
  gemm_tn<4, 0><<<256, 256, 0, stream>>>(Ao, Wot, out, HIDDEN, HIDDEN);  // fp32 C
}